// Round 3
// baseline (94.750 us; speedup 1.0000x reference)
//
#include <hip/hip_runtime.h>
#include <hip/hip_fp16.h>

#define N 2048
#define ONW 4096
#define TW 128                        // tile width (pixels)
#define TH 32                        // tile height (pixels)
#define HW 132                        // halo tile width (ints)
#define HH 36                        // halo tile height
#define HELEMS (HW * HH)              // 4752
#define LUT_ENTRIES 12288
#define LUT_BYTES (LUT_ENTRIES * 8)   // 98304 (fp16 LUT)
#define SMEM_BYTES (LUT_BYTES + 2 * HELEMS * 4)  // 136320 <= 160K

typedef _Float16 half4v __attribute__((ext_vector_type(4)));
typedef float fvec4 __attribute__((ext_vector_type(4)));

__device__ __forceinline__ int reflect(int i) {
    i = i < 0 ? -i : i;
    return i >= N ? 2 * N - 2 - i : i;
}

// compute the 12 LUT indices for one output pixel (pi,pj); fully
// constant-folds when called with literal pi/pj under unrolled loops
__device__ __forceinline__ void calc_idx(const int n[6][6], int pi, int pj, int* idx)
{
    const int bo[3][2] = {{0, 1}, {1, 1}, {1, 2}};
    const int co[3][2] = {{0, 2}, {2, 2}, {2, 1}};
    const int a8 = n[2 + pi][2 + pj] << 8;
    #pragma unroll
    for (int r = 0; r < 4; ++r) {
        #pragma unroll
        for (int k = 0; k < 3; ++k) {
            const int bp = bo[k][0], bq = bo[k][1];
            const int cp = co[k][0], cq = co[k][1];
            const int bdi = (r == 0) ? bp : (r == 1) ? bq : (r == 2) ? -bp : -bq;
            const int bdj = (r == 0) ? bq : (r == 1) ? -bp : (r == 2) ? -bq : bp;
            const int cdi = (r == 0) ? cp : (r == 1) ? cq : (r == 2) ? -cp : -cq;
            const int cdj = (r == 0) ? cq : (r == 1) ? -cp : (r == 2) ? -cq : cp;
            const int bv = n[pi + 2 + bdi][pj + 2 + bdj];
            const int cv = n[pi + 2 + cdi][pj + 2 + cdj];
            idx[r * 3 + k] = (k * 4096 + a8) + (bv * 16 + cv);
        }
    }
}

// sum the 3 k-terms per rotation and scatter into the 2x2 sub-pixel acc
__device__ __forceinline__ void consume(const half4v* v, float* o)
{
    #pragma unroll
    for (int r = 0; r < 4; ++r) {
        half4v S = v[3 * r] + v[3 * r + 1] + v[3 * r + 2];
        const float x = (float)S.x, y = (float)S.y;
        const float z = (float)S.z, w = (float)S.w;
        if (r == 0)      { o[0] += x; o[1] += y; o[2] += z; o[3] += w; }
        else if (r == 1) { o[0] += z; o[1] += x; o[2] += w; o[3] += y; }
        else if (r == 2) { o[0] += w; o[1] += z; o[2] += y; o[3] += x; }
        else             { o[0] += y; o[1] += w; o[2] += x; o[3] += z; }
    }
}

// one-time fp32 -> fp16 LUT conversion into workspace (same cvt rounding
// as the per-block path -> bit-identical results)
__global__ __launch_bounds__(1024) void lut_convert_kernel(
    const float4* __restrict__ w4, half4v* __restrict__ lut16)
{
    const int i = (int)blockIdx.x * 1024 + (int)threadIdx.x;  // 12 * 1024 = 12288
    float4 v = w4[i];
    half4v h;
    h.x = (_Float16)v.x; h.y = (_Float16)v.y;
    h.z = (_Float16)v.z; h.w = (_Float16)v.w;
    lut16[i] = h;
}

template<bool PRE>
__global__ __launch_bounds__(1024, 4) void hdblut_kernel(
    const int* __restrict__ img, const float4* __restrict__ w4,
    const float4* __restrict__ lut16g, float* __restrict__ out)
{
    extern __shared__ unsigned char smem[];
    half4v* lut = (half4v*)smem;
    int* bufs = (int*)(smem + LUT_BYTES);

    const int tx = threadIdx.x;            // 0..63  (one wave = one ty row)
    const int ty = threadIdx.y;            // 0..15
    const int tid = ty * 64 + tx;

    // XCD-aware bijective swizzle: hardware round-robins blockIdx across the
    // 8 XCDs; remap so XCD k owns orig in [32k, 32k+32) = 2 contiguous
    // y-bands -> 2 MB img slice + 98 KB LUT resident in that XCD's 4 MB L2.
    const int bid = (int)blockIdx.x;
    const int orig = ((bid & 7) << 5) | (bid >> 3);
    const int x0 = (orig & 15) * TW;        // 16 x-strips
    const int y0 = (orig >> 4) * (TH * 4);  // 16 y-bands, 4 tiles each

    // 1) LUT into LDS (once per block)
    if (PRE) {
        // pre-converted fp16 LUT: 98 KB = 6144 b128 loads, 6 per thread
        float4* lutf4 = (float4*)smem;
        #pragma unroll
        for (int i = 0; i < 6; ++i) {
            int j = tid + i * 1024;
            lutf4[j] = lut16g[j];
        }
    } else {
        // fallback: fp32 -> fp16 per block
        #pragma unroll
        for (int i = 0; i < 12; ++i) {
            int j = tid + i * 1024;
            float4 v = w4[j];
            half4v h;
            h.x = (_Float16)v.x; h.y = (_Float16)v.y;
            h.z = (_Float16)v.z; h.w = (_Float16)v.w;
            lut[j] = h;
        }
    }

    // 2) tile 0 halo load (direct to LDS)
    for (int e = tid; e < HELEMS; e += 1024) {
        int rr = e / HW, cc = e - rr * HW;
        bufs[e] = img[reflect(y0 + rr - 2) * N + reflect(x0 + cc - 2)];
    }
    __syncthreads();

    const float s = 1.0f / 3.0f;
    fvec4* o4 = (fvec4*)out;

    int pre[5];
    #pragma unroll 1
    for (int t = 0; t < 4; ++t) {
        int* cur = bufs + (t & 1) * HELEMS;
        int* nxt = bufs + ((t + 1) & 1) * HELEMS;

        // prefetch next tile into registers (latency hidden by compute)
        if (t < 3) {
            const int yb = y0 + (t + 1) * TH;
            #pragma unroll
            for (int u = 0; u < 5; ++u) {
                int e = tid + u * 1024;
                if (e < HELEMS) {
                    int rr = e / HW, cc = e - rr * HW;
                    pre[u] = img[reflect(yb + rr - 2) * N + reflect(x0 + cc - 2)];
                }
            }
        }

        // 3) 6x6 neighborhood for this thread's 2x2 pixel patch
        int n[6][6];
        {
            const int r0 = 2 * ty, c0 = 2 * tx;
            #pragma unroll
            for (int r = 0; r < 6; ++r)
                #pragma unroll
                for (int j = 0; j < 3; ++j) {
                    int2 t2 = *(const int2*)&cur[(r0 + r) * HW + c0 + 2 * j];
                    n[r][2 * j] = t2.x; n[r][2 * j + 1] = t2.y;
                }
        }

        float acc[2][2][4];
        #pragma unroll
        for (int i = 0; i < 2; ++i)
            #pragma unroll
            for (int j = 0; j < 2; ++j)
                #pragma unroll
                for (int c = 0; c < 4; ++c) acc[i][j][c] = 0.f;

        // 4) software-pipelined gathers: 4 groups of 12 (one per pixel),
        //    depth 2 in flight, consume one group behind issue
        {
            int idx[12];
            half4v vA[12], vB[12], vC[12], vD[12];

            calc_idx(n, 0, 0, idx);
            #pragma unroll
            for (int i = 0; i < 12; ++i) vA[i] = lut[idx[i]];
            __builtin_amdgcn_sched_group_barrier(0x100, 12, 0);

            calc_idx(n, 0, 1, idx);
            #pragma unroll
            for (int i = 0; i < 12; ++i) vB[i] = lut[idx[i]];
            __builtin_amdgcn_sched_group_barrier(0x100, 12, 0);

            consume(vA, acc[0][0]);

            calc_idx(n, 1, 0, idx);
            #pragma unroll
            for (int i = 0; i < 12; ++i) vC[i] = lut[idx[i]];
            __builtin_amdgcn_sched_group_barrier(0x100, 12, 0);

            consume(vB, acc[0][1]);

            calc_idx(n, 1, 1, idx);
            #pragma unroll
            for (int i = 0; i < 12; ++i) vD[i] = lut[idx[i]];
            __builtin_amdgcn_sched_group_barrier(0x100, 12, 0);

            consume(vC, acc[1][0]);
            consume(vD, acc[1][1]);
        }

        // 5) wave-contiguous non-temporal stores (out has zero reuse;
        //    bypass L2 so LUT/img stay resident)
        const int py = y0 + t * TH + 2 * ty;
        const int ox = (x0 + 2 * tx) * 2;
        {
            fvec4 v0 = {acc[0][0][0] * s, acc[0][0][1] * s, acc[0][1][0] * s, acc[0][1][1] * s};
            fvec4 v1 = {acc[0][0][2] * s, acc[0][0][3] * s, acc[0][1][2] * s, acc[0][1][3] * s};
            fvec4 v2 = {acc[1][0][0] * s, acc[1][0][1] * s, acc[1][1][0] * s, acc[1][1][1] * s};
            fvec4 v3 = {acc[1][0][2] * s, acc[1][0][3] * s, acc[1][1][2] * s, acc[1][1][3] * s};
            __builtin_nontemporal_store(v0, &o4[((2 * py + 0) * ONW + ox) >> 2]);
            __builtin_nontemporal_store(v1, &o4[((2 * py + 1) * ONW + ox) >> 2]);
            __builtin_nontemporal_store(v2, &o4[((2 * py + 2) * ONW + ox) >> 2]);
            __builtin_nontemporal_store(v3, &o4[((2 * py + 3) * ONW + ox) >> 2]);
        }

        // commit prefetched tile to the other LDS buffer
        if (t < 3) {
            #pragma unroll
            for (int u = 0; u < 5; ++u) {
                int e = tid + u * 1024;
                if (e < HELEMS) nxt[e] = pre[u];
            }
        }
        __syncthreads();
    }
}

extern "C" void kernel_launch(void* const* d_in, const int* in_sizes, int n_in,
                              void* d_out, int out_size, void* d_ws, size_t ws_size,
                              hipStream_t stream)
{
    const int* img = (const int*)d_in[0];
    const float4* w4 = (const float4*)d_in[1];
    float* out = (float*)d_out;

    if (d_ws != nullptr && ws_size >= (size_t)LUT_BYTES) {
        (void)hipFuncSetAttribute(reinterpret_cast<const void*>(&hdblut_kernel<true>),
                                  hipFuncAttributeMaxDynamicSharedMemorySize, SMEM_BYTES);
        lut_convert_kernel<<<dim3(12), dim3(1024), 0, stream>>>(w4, (half4v*)d_ws);
        hdblut_kernel<true><<<dim3(256), dim3(64, 16), SMEM_BYTES, stream>>>(
            img, w4, (const float4*)d_ws, out);
    } else {
        (void)hipFuncSetAttribute(reinterpret_cast<const void*>(&hdblut_kernel<false>),
                                  hipFuncAttributeMaxDynamicSharedMemorySize, SMEM_BYTES);
        hdblut_kernel<false><<<dim3(256), dim3(64, 16), SMEM_BYTES, stream>>>(
            img, w4, nullptr, out);
    }
}

// Round 4
// 93.471 us; speedup vs baseline: 1.0137x; 1.0137x over previous
//
#include <hip/hip_runtime.h>
#include <hip/hip_fp16.h>

#define N 2048
#define ONW 4096
#define TW 128                        // tile width (pixels)
#define TH 32                         // tile height (pixels)
#define HW 132                        // halo tile width (ints)
#define HH 36                        // halo tile height
#define HELEMS (HW * HH)              // 4752
#define LUT_ENTRIES 12288
#define LUT_BYTES (LUT_ENTRIES * 8)   // 98304 (fp16 LUT)
#define SMEM_BYTES (LUT_BYTES + 2 * HELEMS * 4)  // 136320 <= 160K

typedef _Float16 half4v __attribute__((ext_vector_type(4)));
typedef float fvec4 __attribute__((ext_vector_type(4)));

__device__ __forceinline__ int reflect(int i) {
    i = i < 0 ? -i : i;
    return i >= N ? 2 * N - 2 - i : i;
}

// compute the 12 LUT indices for one output pixel (pi,pj); fully
// constant-folds when called with literal pi/pj under unrolled loops
__device__ __forceinline__ void calc_idx(const int n[6][6], int pi, int pj, int* idx)
{
    const int bo[3][2] = {{0, 1}, {1, 1}, {1, 2}};
    const int co[3][2] = {{0, 2}, {2, 2}, {2, 1}};
    const int a8 = n[2 + pi][2 + pj] << 8;
    #pragma unroll
    for (int r = 0; r < 4; ++r) {
        #pragma unroll
        for (int k = 0; k < 3; ++k) {
            const int bp = bo[k][0], bq = bo[k][1];
            const int cp = co[k][0], cq = co[k][1];
            const int bdi = (r == 0) ? bp : (r == 1) ? bq : (r == 2) ? -bp : -bq;
            const int bdj = (r == 0) ? bq : (r == 1) ? -bp : (r == 2) ? -bq : bp;
            const int cdi = (r == 0) ? cp : (r == 1) ? cq : (r == 2) ? -cp : -cq;
            const int cdj = (r == 0) ? cq : (r == 1) ? -cp : (r == 2) ? -cq : cp;
            const int bv = n[pi + 2 + bdi][pj + 2 + bdj];
            const int cv = n[pi + 2 + cdi][pj + 2 + cdj];
            idx[r * 3 + k] = (k * 4096 + a8) + (bv * 16 + cv);
        }
    }
}

// sum the 3 k-terms per rotation and scatter into the 2x2 sub-pixel acc
__device__ __forceinline__ void consume(const half4v* v, float* o)
{
    #pragma unroll
    for (int r = 0; r < 4; ++r) {
        half4v S = v[3 * r] + v[3 * r + 1] + v[3 * r + 2];
        const float x = (float)S.x, y = (float)S.y;
        const float z = (float)S.z, w = (float)S.w;
        if (r == 0)      { o[0] += x; o[1] += y; o[2] += z; o[3] += w; }
        else if (r == 1) { o[0] += z; o[1] += x; o[2] += w; o[3] += y; }
        else if (r == 2) { o[0] += w; o[1] += z; o[2] += y; o[3] += x; }
        else             { o[0] += y; o[1] += w; o[2] += x; o[3] += z; }
    }
}

__global__ __launch_bounds__(1024, 4) void hdblut_kernel(
    const int* __restrict__ img, const float4* __restrict__ w4,
    float* __restrict__ out)
{
    extern __shared__ unsigned char smem[];
    half4v* lut = (half4v*)smem;
    int* bufs = (int*)(smem + LUT_BYTES);

    const int tx = threadIdx.x;            // 0..63  (one wave = one ty row)
    const int ty = threadIdx.y;            // 0..15
    const int tid = ty * 64 + tx;

    // XCD-aware bijective swizzle (256 % 8 == 0): XCD k owns orig in
    // [32k, 32k+32) = 2 contiguous y-bands -> halo-row sharing and the
    // per-block LUT stream become local-L2 hits.
    const int bid = (int)blockIdx.x;
    const int orig = ((bid & 7) << 5) | (bid >> 3);
    const int x0 = (orig & 15) * TW;        // 16 x-strips
    const int y0 = (orig >> 4) * (TH * 4);  // 16 y-bands, 4 tiles each

    // 1) fp32 -> fp16 LUT into LDS, two-phase: issue all 12 global loads
    //    first (full vmcnt depth), then convert + ds_write
    {
        float4 lv[12];
        #pragma unroll
        for (int i = 0; i < 12; ++i) lv[i] = w4[tid + i * 1024];
        #pragma unroll
        for (int i = 0; i < 12; ++i) {
            half4v h;
            h.x = (_Float16)lv[i].x; h.y = (_Float16)lv[i].y;
            h.z = (_Float16)lv[i].z; h.w = (_Float16)lv[i].w;
            lut[tid + i * 1024] = h;
        }
    }

    // 2) tile 0 halo load (direct to LDS)
    for (int e = tid; e < HELEMS; e += 1024) {
        int rr = e / HW, cc = e - rr * HW;
        bufs[e] = img[reflect(y0 + rr - 2) * N + reflect(x0 + cc - 2)];
    }
    __syncthreads();

    const float s = 1.0f / 3.0f;
    fvec4* o4 = (fvec4*)out;

    int pre[5];
    #pragma unroll 1
    for (int t = 0; t < 4; ++t) {
        int* cur = bufs + (t & 1) * HELEMS;
        int* nxt = bufs + ((t + 1) & 1) * HELEMS;

        // prefetch next tile into registers (latency hidden by compute)
        if (t < 3) {
            const int yb = y0 + (t + 1) * TH;
            #pragma unroll
            for (int u = 0; u < 5; ++u) {
                int e = tid + u * 1024;
                if (e < HELEMS) {
                    int rr = e / HW, cc = e - rr * HW;
                    pre[u] = img[reflect(yb + rr - 2) * N + reflect(x0 + cc - 2)];
                }
            }
        }

        // 3) 6x6 neighborhood for this thread's 2x2 pixel patch
        int n[6][6];
        {
            const int r0 = 2 * ty, c0 = 2 * tx;
            #pragma unroll
            for (int r = 0; r < 6; ++r)
                #pragma unroll
                for (int j = 0; j < 3; ++j) {
                    int2 t2 = *(const int2*)&cur[(r0 + r) * HW + c0 + 2 * j];
                    n[r][2 * j] = t2.x; n[r][2 * j + 1] = t2.y;
                }
        }

        float acc[2][2][4];
        #pragma unroll
        for (int i = 0; i < 2; ++i)
            #pragma unroll
            for (int j = 0; j < 2; ++j)
                #pragma unroll
                for (int c = 0; c < 4; ++c) acc[i][j][c] = 0.f;

        // 4) software-pipelined gathers: 4 groups of 12 (one per pixel),
        //    depth 2 in flight, consume one group behind issue
        {
            int idx[12];
            half4v vA[12], vB[12], vC[12], vD[12];

            calc_idx(n, 0, 0, idx);
            #pragma unroll
            for (int i = 0; i < 12; ++i) vA[i] = lut[idx[i]];
            __builtin_amdgcn_sched_group_barrier(0x100, 12, 0);

            calc_idx(n, 0, 1, idx);
            #pragma unroll
            for (int i = 0; i < 12; ++i) vB[i] = lut[idx[i]];
            __builtin_amdgcn_sched_group_barrier(0x100, 12, 0);

            consume(vA, acc[0][0]);

            calc_idx(n, 1, 0, idx);
            #pragma unroll
            for (int i = 0; i < 12; ++i) vC[i] = lut[idx[i]];
            __builtin_amdgcn_sched_group_barrier(0x100, 12, 0);

            consume(vB, acc[0][1]);

            calc_idx(n, 1, 1, idx);
            #pragma unroll
            for (int i = 0; i < 12; ++i) vD[i] = lut[idx[i]];
            __builtin_amdgcn_sched_group_barrier(0x100, 12, 0);

            consume(vC, acc[1][0]);
            consume(vD, acc[1][1]);
        }

        // 5) wave-contiguous non-temporal stores (out has zero reuse;
        //    bypass L2 so LUT/img stay resident)
        const int py = y0 + t * TH + 2 * ty;
        const int ox = (x0 + 2 * tx) * 2;
        {
            fvec4 v0 = {acc[0][0][0] * s, acc[0][0][1] * s, acc[0][1][0] * s, acc[0][1][1] * s};
            fvec4 v1 = {acc[0][0][2] * s, acc[0][0][3] * s, acc[0][1][2] * s, acc[0][1][3] * s};
            fvec4 v2 = {acc[1][0][0] * s, acc[1][0][1] * s, acc[1][1][0] * s, acc[1][1][1] * s};
            fvec4 v3 = {acc[1][0][2] * s, acc[1][0][3] * s, acc[1][1][2] * s, acc[1][1][3] * s};
            __builtin_nontemporal_store(v0, &o4[((2 * py + 0) * ONW + ox) >> 2]);
            __builtin_nontemporal_store(v1, &o4[((2 * py + 1) * ONW + ox) >> 2]);
            __builtin_nontemporal_store(v2, &o4[((2 * py + 2) * ONW + ox) >> 2]);
            __builtin_nontemporal_store(v3, &o4[((2 * py + 3) * ONW + ox) >> 2]);
        }

        // commit prefetched tile to the other LDS buffer
        if (t < 3) {
            #pragma unroll
            for (int u = 0; u < 5; ++u) {
                int e = tid + u * 1024;
                if (e < HELEMS) nxt[e] = pre[u];
            }
        }
        __syncthreads();
    }
}

extern "C" void kernel_launch(void* const* d_in, const int* in_sizes, int n_in,
                              void* d_out, int out_size, void* d_ws, size_t ws_size,
                              hipStream_t stream)
{
    const int* img = (const int*)d_in[0];
    const float4* w4 = (const float4*)d_in[1];
    float* out = (float*)d_out;
    (void)hipFuncSetAttribute(reinterpret_cast<const void*>(hdblut_kernel),
                              hipFuncAttributeMaxDynamicSharedMemorySize, SMEM_BYTES);
    hdblut_kernel<<<dim3(256), dim3(64, 16), SMEM_BYTES, stream>>>(img, w4, out);
}